// Round 3
// baseline (666.437 us; speedup 1.0000x reference)
//
#include <hip/hip_runtime.h>

// EdgeGate: out[e] = silu(f(e) @ W1 + b1) @ W2 + b2,
//   f(e) = [|H_u - H_v| (128), H_u*H_v (128), S_e, F_e]   (258)
//
// R15 (post-mortem of R14's FETCH 55MB->1.3GB blowup): static CONTIGUOUS
// spans gave each of 512 blocks a private position in the sorted edge list
// -> 64 independent b-streams per segment -> per-XCD L2 thrash -> every 16B
// gather missed to HBM (plus out[] scatter-line evictions: WRITE 267MB).
// R12's ticket queue had implicitly kept all blocks of a segment temporally
// ALIGNED in the sorted order; that alignment, not the queue, was the value.
// Fix: STATIC INTERLEAVE. wave-slot s = rank*8+wave (512 slots/segment)
// processes groups g = s + 512*i. Instantaneous window = 512 consecutive
// 16-edge groups (~8k edges): b-rows ~1.4MB + hot a-rows 1.6MB < 4MB L2 per
// XCD. Zero atomics, zero main-loop barriers, natural pacing. Also:
// software-pipelined recs read (prefetch recs[g+512] before computing tile
// g) -> one gather round-trip per tile instead of two serial ones.
// Kept: S/F/b1 folded into MFMA K-chunk 8, W2 in regs, fused cvt+hist.

typedef _Float16       half8   __attribute__((ext_vector_type(8)));
typedef _Float16       half4v  __attribute__((ext_vector_type(4)));
typedef unsigned short ushort8 __attribute__((ext_vector_type(8)));
typedef float          f32x4   __attribute__((ext_vector_type(4)));

#define NSEG       8
#define W1T_STRIDE 288   // halves per n-row: 9 K-chunks x 32

__device__ __forceinline__ float silu_f(float x) {
    return x / (1.0f + __expf(-x));
}

__device__ __forceinline__ void canon(int u, int v, int& a, int& b) {
    const int sw = (u ^ v) & 1;       // balanced, symmetric in (u,v)
    a = sw ? v : u;
    b = sw ? u : v;
}

// ---------------- pre-passes ----------------
// hist zeroed by hipMemsetAsync before cvt_hist_kernel.

__global__ __launch_bounds__(256)
void cvt_hist_kernel(const float* __restrict__ H, _Float16* __restrict__ Hh,
                     int n4, const int* __restrict__ eidx,
                     int* __restrict__ hist, int E, int ASZ, int BBINS) {
    int i = blockIdx.x * blockDim.x + threadIdx.x;
    if (i < n4) {
        const float4 f = ((const float4*)H)[i];
        half4v h;
        h[0] = (_Float16)f.x; h[1] = (_Float16)f.y;
        h[2] = (_Float16)f.z; h[3] = (_Float16)f.w;
        ((half4v*)Hh)[i] = h;
    }
    if (i < E) {
        int a, b;
        canon(eidx[i], eidx[E + i], a, b);
        atomicAdd(&hist[(a / ASZ) * BBINS + (b >> 3)], 1);
    }
}

// intra-block exclusive scan; bsum = block totals
__global__ __launch_bounds__(256)
void scan1_kernel(int* __restrict__ hist, int* __restrict__ bsum, int NB) {
    __shared__ int s[256];
    const int t = threadIdx.x;
    const int i = blockIdx.x * 256 + t;
    const int v = (i < NB) ? hist[i] : 0;
    s[t] = v;
    __syncthreads();
    for (int off = 1; off < 256; off <<= 1) {
        const int x = (t >= off) ? s[t - off] : 0;
        __syncthreads();
        s[t] += x;
        __syncthreads();
    }
    if (i < NB) hist[i] = s[t] - v;
    if (t == 255) bsum[blockIdx.x] = s[255];
}

// exclusive-scan bsum; then segment bounds vbs[0..NSEG]
__global__ __launch_bounds__(256)
void scan2_kernel(int* __restrict__ bsum, int nb1,
                  const int* __restrict__ hist, int* __restrict__ vbs,
                  int BBINS, int E) {
    __shared__ int s[256];
    const int t = threadIdx.x;
    const int v = (t < nb1) ? bsum[t] : 0;
    s[t] = v;
    __syncthreads();
    for (int off = 1; off < 256; off <<= 1) {
        const int x = (t >= off) ? s[t - off] : 0;
        __syncthreads();
        s[t] += x;
        __syncthreads();
    }
    if (t < nb1) bsum[t] = s[t] - v;   // exclusive
    __syncthreads();
    if (t < NSEG) {
        const int idx = t * BBINS;
        vbs[t] = hist[idx] + bsum[idx >> 8];
    } else if (t == NSEG) {
        vbs[NSEG] = E;
    }
}

__global__ __launch_bounds__(256)
void scatter_kernel(const int* __restrict__ eidx, const float* __restrict__ Se,
                    const float* __restrict__ Fe, int* __restrict__ ofs,
                    const int* __restrict__ bsum,
                    int4* __restrict__ recs, int E, int ASZ, int BBINS) {
    int e = blockIdx.x * blockDim.x + threadIdx.x;
    if (e < E) {
        int a, b;
        canon(eidx[e], eidx[E + e], a, b);
        const int key = (a / ASZ) * BBINS + (b >> 3);
        const int pos = atomicAdd(&ofs[key], 1) + bsum[key >> 8];
        _Float16 sh = (_Float16)Se[e];
        _Float16 fh = (_Float16)Fe[e];
        unsigned pk = (unsigned)*(unsigned short*)&sh
                    | ((unsigned)*(unsigned short*)&fh << 16);
        recs[pos] = make_int4(a, b, e, (int)pk);
    }
}

// ---------------- W1 LDS staging ----------------
// w1t[n][kp] f16, kp = c*32 + k32, c = 0..8.
// c<8: src row = (c&1)*128 + (c>>1)*32 + k32 (even c -> |diff| rows, odd ->
//      prod rows; zero-interleave A-frags). 16B blocks kb at kb^(n&7).
// c==8 (kb 32..35, UNswizzled): k32==0 -> W1 row 256 (S weight),
//      k32==1 -> row 257 (F weight), k32==2 -> b1, else 0.

__device__ __forceinline__ void stage_w1(const float* __restrict__ W1,
                                         const float* __restrict__ b1,
                                         _Float16* __restrict__ w1t, int tid) {
    const int n = tid & 127;
    const int g = tid >> 7;
    #pragma unroll
    for (int i = 0; i < 9; ++i) {
        const int kb = g + (i << 2);           // 0..35
        half8 tmp;
        if (kb < 32) {
            #pragma unroll
            for (int j = 0; j < 8; ++j) {
                const int kp  = (kb << 3) + j;
                const int c   = kp >> 5;
                const int k32 = kp & 31;
                const int src = ((c & 1) << 7) + ((c >> 1) << 5) + k32;
                tmp[j] = (_Float16)W1[src * 128 + n];
            }
            *(half8*)&w1t[n * W1T_STRIDE + ((kb ^ (n & 7)) << 3)] = tmp;
        } else {
            const int k32b = (kb - 32) << 3;   // 0,8,16,24
            #pragma unroll
            for (int j = 0; j < 8; ++j) {
                const int k32 = k32b + j;
                float v = 0.f;
                if (k32 == 0)      v = W1[32768 + n];   // row 256
                else if (k32 == 1) v = W1[32896 + n];   // row 257
                else if (k32 == 2) v = b1[n];
                tmp[j] = (_Float16)v;
            }
            *(half8*)&w1t[n * W1T_STRIDE + (kb << 3)] = tmp;
        }
    }
}

// ---------------- main tile compute (one 16-edge group per wave) ----------------
// r = this lane's record (prefetched by caller).

__device__ __forceinline__ void edge_tile16(
    const _Float16* __restrict__ Hh, const _Float16* __restrict__ w1t,
    int4 r, f32x4 w2a, f32x4 w2b, float b2v, float* __restrict__ out,
    int ebase, int elim, int q, int cb, int swz)
{
    const int a = r.x, b = r.y, oe = r.z;
    const unsigned pk = (unsigned)r.w;
    const unsigned short sl = (unsigned short)(pk & 0xFFFF);
    const unsigned short fl = (unsigned short)(pk >> 16);

    const _Float16* up = Hh + (size_t)a * 128;
    const _Float16* vp = Hh + (size_t)b * 128;

    f32x4 acc[8];
    #pragma unroll
    for (int t = 0; t < 8; ++t) acc[t] = (f32x4){0.f, 0.f, 0.f, 0.f};

    #pragma unroll
    for (int c8 = 0; c8 < 4; ++c8) {
        const half8 u8 = *(const half8*)(up + (c8 << 5) + (q << 3));
        const half8 v8 = *(const half8*)(vp + (c8 << 5) + (q << 3));
        half8 d8 = u8 - v8;
        ushort8 du = *(ushort8*)&d8;
        du = du & (unsigned short)0x7FFF;          // |diff|
        const half8 ae = *(half8*)&du;             // even-chunk A-frag
        const half8 ao = u8 * v8;                  // odd-chunk  A-frag

        const int kb0 = ((c8 << 3) + q) ^ swz;        // even chunk 2*c8
        const int kb1 = ((c8 << 3) + 4 + q) ^ swz;    // odd  chunk 2*c8+1
        #pragma unroll
        for (int t = 0; t < 8; ++t) {
            const half8 b0 = *(const half8*)&w1t[((t << 4) + cb) * W1T_STRIDE + (kb0 << 3)];
            acc[t] = __builtin_amdgcn_mfma_f32_16x16x32_f16(ae, b0, acc[t], 0, 0, 0);
        }
        #pragma unroll
        for (int t = 0; t < 8; ++t) {
            const half8 b1f = *(const half8*)&w1t[((t << 4) + cb) * W1T_STRIDE + (kb1 << 3)];
            acc[t] = __builtin_amdgcn_mfma_f32_16x16x32_f16(ao, b1f, acc[t], 0, 0, 0);
        }
    }

    // K-chunk 8: A = [S, F, 1, 0...], B rows = [w256; w257; b1; 0...]
    half8 aE;
    #pragma unroll
    for (int j = 0; j < 8; ++j) aE[j] = (_Float16)0.f;
    if (q == 0) {
        aE[0] = *(const _Float16*)&sl;
        aE[1] = *(const _Float16*)&fl;
        aE[2] = (_Float16)1.0f;
    }
    #pragma unroll
    for (int t = 0; t < 8; ++t) {
        const half8 bE = *(const half8*)&w1t[((t << 4) + cb) * W1T_STRIDE + ((32 + q) << 3)];
        acc[t] = __builtin_amdgcn_mfma_f32_16x16x32_f16(aE, bE, acc[t], 0, 0, 0);
    }

    // epilogue: silu(acc) dot W2 only (S/F/b1 already inside acc)
    int oe_r[4];
    #pragma unroll
    for (int rr = 0; rr < 4; ++rr) oe_r[rr] = __shfl(oe, (q << 2) + rr);

    float rs[4] = {0.f, 0.f, 0.f, 0.f};
    #pragma unroll
    for (int t = 0; t < 8; ++t) {
        const float w2c = (t < 4) ? w2a[t] : w2b[t - 4];
        const f32x4 av = acc[t];
        #pragma unroll
        for (int rr = 0; rr < 4; ++rr)
            rs[rr] += silu_f(av[rr]) * w2c;
    }

    #pragma unroll
    for (int off = 1; off < 16; off <<= 1) {
        #pragma unroll
        for (int rr = 0; rr < 4; ++rr) rs[rr] += __shfl_xor(rs[rr], off);
    }

    if (cb == 0) {
        #pragma unroll
        for (int rr = 0; rr < 4; ++rr) {
            const int pe = ebase + (q << 2) + rr;
            if (pe < elim) out[oe_r[rr]] = rs[rr] + b2v;
        }
    }
}

// ---------------- main kernel: static interleave, no atomics/barriers ----------------

__global__ __launch_bounds__(512, 4)
void edgegate_seg(const _Float16* __restrict__ Hh,
                  const int4*  __restrict__ recs,
                  const int*   __restrict__ vbs,   // [9] segment edge bounds
                  const float* __restrict__ W1,
                  const float* __restrict__ b1,
                  const float* __restrict__ W2,
                  const float* __restrict__ b2,
                  float*       __restrict__ out)
{
    __shared__ _Float16 w1t[128 * W1T_STRIDE];   // 73,728 B
    const int tid = threadIdx.x;
    stage_w1(W1, b1, w1t, tid);

    const int lane = tid & 63;
    const int wave = tid >> 6;
    const int q    = lane >> 4;
    const int cb   = lane & 15;
    const int swz  = cb & 7;
    const float b2v = b2[0];
    f32x4 w2a, w2b;
    #pragma unroll
    for (int t = 0; t < 4; ++t) {
        w2a[t] = W2[(t << 4) + cb];
        w2b[t] = W2[((t + 4) << 4) + cb];
    }

    // seg from blockIdx (coverage guaranteed); on round-robin dispatch
    // blockIdx&7 == XCC_ID, so the counting-sort segment stays XCD-local.
    const int seg  = blockIdx.x & (NSEG - 1);
    const int rank = blockIdx.x >> 3;            // 0..63 within segment

    __syncthreads();   // w1t ready; only barrier in the kernel

    const int vs  = vbs[seg];
    const int ve  = vbs[seg + 1];
    const int ner = ve - vs;
    if (ner <= 0) return;
    const int ngrp = (ner + 15) >> 4;            // 16-edge groups
    const int slot = (rank << 3) + wave;         // 0..511

    // INTERLEAVED traversal: at any instant the segment's 512 wave-slots
    // cover ~512 consecutive groups (~8k sorted edges) -> shared b-window
    // + hot a-rows fit the XCD's 4MB L2. recs[g+512] prefetched so the
    // record gather and the row gathers overlap (one round-trip per tile).
    int g = slot;
    if (g < ngrp) {
        int4 r = recs[min(vs + (g << 4) + cb, ve - 1)];
        while (true) {
            const int gn = g + 512;
            int4 rn = r;
            if (gn < ngrp) rn = recs[min(vs + (gn << 4) + cb, ve - 1)];
            edge_tile16(Hh, w1t, r, w2a, w2b, b2v, out,
                        vs + (g << 4), ve, q, cb, swz);
            if (gn >= ngrp) break;
            r = rn;
            g = gn;
        }
    }
}

// ---------------- fallback (unsorted) ----------------

__global__ __launch_bounds__(512, 4)
void edgegate_fb(const float* __restrict__ H,
                 const _Float16* __restrict__ Hh,
                 const int*   __restrict__ eidx,
                 const float* __restrict__ Se,
                 const float* __restrict__ Fe,
                 const float* __restrict__ W1,
                 const float* __restrict__ b1,
                 const float* __restrict__ W2,
                 const float* __restrict__ b2,
                 float*       __restrict__ out,
                 int E, int ntiles, int useF16)
{
    __shared__ _Float16 w1t[128 * W1T_STRIDE];
    const int tid = threadIdx.x;
    stage_w1(W1, b1, w1t, tid);

    const int lane = tid & 63;
    const int wave = tid >> 6;
    const int q    = lane >> 4;
    const int cb   = lane & 15;
    const int swz  = cb & 7;
    const float b2v = b2[0];
    f32x4 w2a, w2b;
    #pragma unroll
    for (int t = 0; t < 4; ++t) {
        w2a[t] = W2[(t << 4) + cb];
        w2b[t] = W2[((t + 4) << 4) + cb];
    }

    __syncthreads();

    for (int tile = blockIdx.x; tile < ntiles; tile += gridDim.x) {
        const int ebase = tile * 128 + wave * 16;
        int e = ebase + cb;
        if (e >= E) e = E - 1;
        const int u = eidx[e];
        const int v = eidx[E + e];
        const float sfe = Se[e];
        const float ffe = Fe[e];

        f32x4 acc[8];
        #pragma unroll
        for (int t = 0; t < 8; ++t) acc[t] = (f32x4){0.f, 0.f, 0.f, 0.f};

        #pragma unroll
        for (int c8 = 0; c8 < 4; ++c8) {
            half8 ae, ao;
            if (useF16) {
                const _Float16* up = Hh + (size_t)u * 128;
                const _Float16* vp = Hh + (size_t)v * 128;
                const half8 u8 = *(const half8*)(up + (c8 << 5) + (q << 3));
                const half8 v8 = *(const half8*)(vp + (c8 << 5) + (q << 3));
                half8 d8 = u8 - v8;
                ushort8 du = *(ushort8*)&d8;
                du = du & (unsigned short)0x7FFF;
                ae = *(half8*)&du;
                ao = u8 * v8;
            } else {
                const float* up = H + (size_t)u * 128;
                const float* vp = H + (size_t)v * 128;
                #pragma unroll
                for (int j = 0; j < 8; ++j) {
                    const float uu = up[(c8 << 5) + (q << 3) + j];
                    const float vv = vp[(c8 << 5) + (q << 3) + j];
                    ae[j] = (_Float16)fabsf(uu - vv);
                    ao[j] = (_Float16)(uu * vv);
                }
            }
            const int kb0 = ((c8 << 3) + q) ^ swz;
            const int kb1 = ((c8 << 3) + 4 + q) ^ swz;
            #pragma unroll
            for (int t = 0; t < 8; ++t) {
                const half8 b0 = *(const half8*)&w1t[((t << 4) + cb) * W1T_STRIDE + (kb0 << 3)];
                acc[t] = __builtin_amdgcn_mfma_f32_16x16x32_f16(ae, b0, acc[t], 0, 0, 0);
            }
            #pragma unroll
            for (int t = 0; t < 8; ++t) {
                const half8 b1f = *(const half8*)&w1t[((t << 4) + cb) * W1T_STRIDE + (kb1 << 3)];
                acc[t] = __builtin_amdgcn_mfma_f32_16x16x32_f16(ao, b1f, acc[t], 0, 0, 0);
            }
        }

        // K-chunk 8
        half8 aE;
        #pragma unroll
        for (int j = 0; j < 8; ++j) aE[j] = (_Float16)0.f;
        if (q == 0) {
            aE[0] = (_Float16)sfe;
            aE[1] = (_Float16)ffe;
            aE[2] = (_Float16)1.0f;
        }
        #pragma unroll
        for (int t = 0; t < 8; ++t) {
            const half8 bE = *(const half8*)&w1t[((t << 4) + cb) * W1T_STRIDE + ((32 + q) << 3)];
            acc[t] = __builtin_amdgcn_mfma_f32_16x16x32_f16(aE, bE, acc[t], 0, 0, 0);
        }

        float rs[4] = {0.f, 0.f, 0.f, 0.f};
        #pragma unroll
        for (int t = 0; t < 8; ++t) {
            const float w2c = (t < 4) ? w2a[t] : w2b[t - 4];
            const f32x4 av = acc[t];
            #pragma unroll
            for (int rr = 0; rr < 4; ++rr)
                rs[rr] += silu_f(av[rr]) * w2c;
        }
        #pragma unroll
        for (int off = 1; off < 16; off <<= 1) {
            #pragma unroll
            for (int rr = 0; rr < 4; ++rr) rs[rr] += __shfl_xor(rs[rr], off);
        }

        const int e0 = ebase + (q << 2);
        if (cb == 0) {
            #pragma unroll
            for (int rr = 0; rr < 4; ++rr) {
                const int pe = e0 + rr;
                if (pe < E) out[pe] = rs[rr] + b2v;
            }
        }
    }
}

// ---------------- launch ----------------

static inline size_t align256(size_t x) { return (x + 255) & ~(size_t)255; }

extern "C" void kernel_launch(void* const* d_in, const int* in_sizes, int n_in,
                              void* d_out, int out_size, void* d_ws, size_t ws_size,
                              hipStream_t stream)
{
    const float* H    = (const float*)d_in[0];
    const int*   eidx = (const int*)  d_in[1];
    const float* Se   = (const float*)d_in[2];
    const float* Fe   = (const float*)d_in[3];
    const float* W1   = (const float*)d_in[4];
    const float* b1   = (const float*)d_in[5];
    const float* W2   = (const float*)d_in[6];
    const float* b2   = (const float*)d_in[7];
    float* out = (float*)d_out;

    const int nH     = in_sizes[0];            // 6.4M floats
    const int nNodes = nH / 128;               // 50000
    const int E      = in_sizes[2];            // 600000
    const int n4     = nH / 4;
    const int ntiles = (E + 127) / 128;

    const int ASZ   = (nNodes + NSEG - 1) / NSEG;   // 6250
    const int BBINS = (nNodes + 7) >> 3;            // 6250
    const int NB    = NSEG * BBINS;                 // 50000
    const int nb1   = (NB + 255) / 256;             // 196

    const size_t hhB    = (size_t)nH * sizeof(_Float16);
    const size_t off_g  = align256(hhB);                          // hist
    const size_t off_bs = align256(off_g + (size_t)(NB + 8) * 4); // bsum
    const size_t off_vb = align256(off_bs + 256 * 4);             // vbs[9]
    const size_t off_r  = align256(off_vb + 16 * 4);              // recs
    const size_t need   = off_r + (size_t)E * sizeof(int4);

    if (ws_size >= need && nb1 <= 256) {
        _Float16* Hh   = (_Float16*)((char*)d_ws);
        int*      hist = (int*)     ((char*)d_ws + off_g);
        int*      bsum = (int*)     ((char*)d_ws + off_bs);
        int*      vbs  = (int*)     ((char*)d_ws + off_vb);
        int4*     recs = (int4*)    ((char*)d_ws + off_r);

        const int ncvh = (n4 > E) ? n4 : E;
        hipMemsetAsync(hist, 0, (size_t)(NB + 8) * sizeof(int), stream);
        hipLaunchKernelGGL(cvt_hist_kernel, dim3((ncvh + 255) / 256), dim3(256),
                           0, stream, H, Hh, n4, eidx, hist, E, ASZ, BBINS);
        hipLaunchKernelGGL(scan1_kernel, dim3(nb1), dim3(256), 0, stream,
                           hist, bsum, NB);
        hipLaunchKernelGGL(scan2_kernel, dim3(1), dim3(256), 0, stream,
                           bsum, nb1, hist, vbs, BBINS, E);
        hipLaunchKernelGGL(scatter_kernel, dim3((E + 255) / 256), dim3(256),
                           0, stream, eidx, Se, Fe, hist, bsum, recs,
                           E, ASZ, BBINS);
        hipLaunchKernelGGL(edgegate_seg, dim3(512), dim3(512), 0, stream,
                           Hh, recs, vbs, W1, b1, W2, b2, out);
    } else if (ws_size >= hhB) {
        _Float16* Hh = (_Float16*)d_ws;
        const int grid = (512 < ntiles) ? 512 : ntiles;
        hipLaunchKernelGGL(cvt_hist_kernel, dim3((n4 + 255) / 256), dim3(256),
                           0, stream, H, Hh, n4, eidx, (int*)nullptr, 0, 1, 1);
        hipLaunchKernelGGL(edgegate_fb, dim3(grid), dim3(512), 0, stream,
                           H, Hh, eidx, Se, Fe, W1, b1, W2, b2, out, E, ntiles, 1);
    } else {
        const int grid = (512 < ntiles) ? 512 : ntiles;
        hipLaunchKernelGGL(edgegate_fb, dim3(grid), dim3(512), 0, stream,
                           H, (const _Float16*)nullptr, eidx, Se, Fe, W1, b1, W2, b2,
                           out, E, ntiles, 0);
    }
}

// Round 4
// 282.850 us; speedup vs baseline: 2.3561x; 2.3561x over previous
//
#include <hip/hip_runtime.h>

// EdgeGate: out[e] = silu(f(e) @ W1 + b1) @ W2 + b2,
//   f(e) = [|H_u - H_v| (128), H_u*H_v (128), S_e, F_e]   (258)
//
// R16 (consolidation). R14/R15 post-mortem: static partitions (contiguous
// OR interleaved) cannot hold the segment's blocks in a shared L2 window --
// FETCH stayed 1.3GB both times. R12's ordered ticket queue was PACING, not
// just ordering: blocks can't run ahead of the issue order, so the
// instantaneous working set stays ~128-edge-aligned across the segment
// (FETCH 61MB, 154us proven). Restored verbatim. Grafted on top, each
// independently validated:
//  (a) ticket PREFETCH at block level: tid0 issues next ticket's atomicAdd
//      BEFORE tile compute; the post-compute __syncthreads publishes it.
//      Atomic RT overlaps compute (R13 failed doing this per-wave: vmcnt
//      in-order drain + 6x atomic count; block-level has neither problem).
//  (b) S/F/b1 folded into a 9th MFMA K-chunk (A=[S,F,1,0..], B rows =
//      [w256;w257;b1;0..]); epilogue = silu(acc)*w2 only; W2 in regs.
//      Carried R13-R15, absmax 0.015625 unchanged.
//  (c) fused cvt+hist + hipMemsetAsync zeroing (-1 dispatch).

typedef _Float16       half8   __attribute__((ext_vector_type(8)));
typedef _Float16       half4v  __attribute__((ext_vector_type(4)));
typedef unsigned short ushort8 __attribute__((ext_vector_type(8)));
typedef float          f32x4   __attribute__((ext_vector_type(4)));

#define NSEG       8
#define W1T_STRIDE 288   // halves per n-row: 9 K-chunks x 32

__device__ __forceinline__ float silu_f(float x) {
    return x / (1.0f + __expf(-x));
}

__device__ __forceinline__ void canon(int u, int v, int& a, int& b) {
    const int sw = (u ^ v) & 1;       // balanced, symmetric in (u,v)
    a = sw ? v : u;
    b = sw ? u : v;
}

// ---------------- pre-passes ----------------
// hist (+ctr tail) zeroed by hipMemsetAsync before cvt_hist_kernel.

__global__ __launch_bounds__(256)
void cvt_hist_kernel(const float* __restrict__ H, _Float16* __restrict__ Hh,
                     int n4, const int* __restrict__ eidx,
                     int* __restrict__ hist, int E, int ASZ, int BBINS) {
    int i = blockIdx.x * blockDim.x + threadIdx.x;
    if (i < n4) {
        const float4 f = ((const float4*)H)[i];
        half4v h;
        h[0] = (_Float16)f.x; h[1] = (_Float16)f.y;
        h[2] = (_Float16)f.z; h[3] = (_Float16)f.w;
        ((half4v*)Hh)[i] = h;
    }
    if (i < E) {
        int a, b;
        canon(eidx[i], eidx[E + i], a, b);
        atomicAdd(&hist[(a / ASZ) * BBINS + (b >> 3)], 1);
    }
}

// intra-block exclusive scan; bsum = block totals
__global__ __launch_bounds__(256)
void scan1_kernel(int* __restrict__ hist, int* __restrict__ bsum, int NB) {
    __shared__ int s[256];
    const int t = threadIdx.x;
    const int i = blockIdx.x * 256 + t;
    const int v = (i < NB) ? hist[i] : 0;
    s[t] = v;
    __syncthreads();
    for (int off = 1; off < 256; off <<= 1) {
        const int x = (t >= off) ? s[t - off] : 0;
        __syncthreads();
        s[t] += x;
        __syncthreads();
    }
    if (i < NB) hist[i] = s[t] - v;
    if (t == 255) bsum[blockIdx.x] = s[255];
}

// exclusive-scan bsum; then segment bounds vbs[0..NSEG]
__global__ __launch_bounds__(256)
void scan2_kernel(int* __restrict__ bsum, int nb1,
                  const int* __restrict__ hist, int* __restrict__ vbs,
                  int BBINS, int E) {
    __shared__ int s[256];
    const int t = threadIdx.x;
    const int v = (t < nb1) ? bsum[t] : 0;
    s[t] = v;
    __syncthreads();
    for (int off = 1; off < 256; off <<= 1) {
        const int x = (t >= off) ? s[t - off] : 0;
        __syncthreads();
        s[t] += x;
        __syncthreads();
    }
    if (t < nb1) bsum[t] = s[t] - v;   // exclusive
    __syncthreads();
    if (t < NSEG) {
        const int idx = t * BBINS;
        vbs[t] = hist[idx] + bsum[idx >> 8];
    } else if (t == NSEG) {
        vbs[NSEG] = E;
    }
}

__global__ __launch_bounds__(256)
void scatter_kernel(const int* __restrict__ eidx, const float* __restrict__ Se,
                    const float* __restrict__ Fe, int* __restrict__ ofs,
                    const int* __restrict__ bsum,
                    int4* __restrict__ recs, int E, int ASZ, int BBINS) {
    int e = blockIdx.x * blockDim.x + threadIdx.x;
    if (e < E) {
        int a, b;
        canon(eidx[e], eidx[E + e], a, b);
        const int key = (a / ASZ) * BBINS + (b >> 3);
        const int pos = atomicAdd(&ofs[key], 1) + bsum[key >> 8];
        _Float16 sh = (_Float16)Se[e];
        _Float16 fh = (_Float16)Fe[e];
        unsigned pk = (unsigned)*(unsigned short*)&sh
                    | ((unsigned)*(unsigned short*)&fh << 16);
        recs[pos] = make_int4(a, b, e, (int)pk);
    }
}

// ---------------- W1 LDS staging ----------------
// w1t[n][kp] f16, kp = c*32 + k32, c = 0..8.
// c<8: src row = (c&1)*128 + (c>>1)*32 + k32 (even c -> |diff| rows, odd ->
//      prod rows; zero-interleave A-frags). 16B blocks kb at kb^(n&7).
// c==8 (kb 32..35, UNswizzled): k32==0 -> W1 row 256 (S weight),
//      k32==1 -> row 257 (F weight), k32==2 -> b1, else 0.

__device__ __forceinline__ void stage_w1(const float* __restrict__ W1,
                                         const float* __restrict__ b1,
                                         _Float16* __restrict__ w1t, int tid) {
    const int n = tid & 127;
    const int g = tid >> 7;
    #pragma unroll
    for (int i = 0; i < 9; ++i) {
        const int kb = g + (i << 2);           // 0..35
        half8 tmp;
        if (kb < 32) {
            #pragma unroll
            for (int j = 0; j < 8; ++j) {
                const int kp  = (kb << 3) + j;
                const int c   = kp >> 5;
                const int k32 = kp & 31;
                const int src = ((c & 1) << 7) + ((c >> 1) << 5) + k32;
                tmp[j] = (_Float16)W1[src * 128 + n];
            }
            *(half8*)&w1t[n * W1T_STRIDE + ((kb ^ (n & 7)) << 3)] = tmp;
        } else {
            const int k32b = (kb - 32) << 3;   // 0,8,16,24
            #pragma unroll
            for (int j = 0; j < 8; ++j) {
                const int k32 = k32b + j;
                float v = 0.f;
                if (k32 == 0)      v = W1[32768 + n];   // row 256
                else if (k32 == 1) v = W1[32896 + n];   // row 257
                else if (k32 == 2) v = b1[n];
                tmp[j] = (_Float16)v;
            }
            *(half8*)&w1t[n * W1T_STRIDE + (kb << 3)] = tmp;
        }
    }
}

// ---------------- main tile compute (one 16-edge group per wave) ----------------

__device__ __forceinline__ void edge_tile16(
    const _Float16* __restrict__ Hh, const int4* __restrict__ recs,
    const _Float16* __restrict__ w1t,
    f32x4 w2a, f32x4 w2b, float b2v, float* __restrict__ out,
    int ebase, int elim, int q, int cb, int swz)
{
    const int e = min(ebase + cb, elim - 1);     // clamp; stores guarded
    const int4 r = recs[e];
    const int a = r.x, b = r.y, oe = r.z;
    const unsigned pk = (unsigned)r.w;
    const unsigned short sl = (unsigned short)(pk & 0xFFFF);
    const unsigned short fl = (unsigned short)(pk >> 16);

    const _Float16* up = Hh + (size_t)a * 128;
    const _Float16* vp = Hh + (size_t)b * 128;

    f32x4 acc[8];
    #pragma unroll
    for (int t = 0; t < 8; ++t) acc[t] = (f32x4){0.f, 0.f, 0.f, 0.f};

    #pragma unroll
    for (int c8 = 0; c8 < 4; ++c8) {
        const half8 u8 = *(const half8*)(up + (c8 << 5) + (q << 3));
        const half8 v8 = *(const half8*)(vp + (c8 << 5) + (q << 3));
        half8 d8 = u8 - v8;
        ushort8 du = *(ushort8*)&d8;
        du = du & (unsigned short)0x7FFF;          // |diff|
        const half8 ae = *(half8*)&du;             // even-chunk A-frag
        const half8 ao = u8 * v8;                  // odd-chunk  A-frag

        const int kb0 = ((c8 << 3) + q) ^ swz;        // even chunk 2*c8
        const int kb1 = ((c8 << 3) + 4 + q) ^ swz;    // odd  chunk 2*c8+1
        #pragma unroll
        for (int t = 0; t < 8; ++t) {
            const half8 b0 = *(const half8*)&w1t[((t << 4) + cb) * W1T_STRIDE + (kb0 << 3)];
            acc[t] = __builtin_amdgcn_mfma_f32_16x16x32_f16(ae, b0, acc[t], 0, 0, 0);
        }
        #pragma unroll
        for (int t = 0; t < 8; ++t) {
            const half8 b1f = *(const half8*)&w1t[((t << 4) + cb) * W1T_STRIDE + (kb1 << 3)];
            acc[t] = __builtin_amdgcn_mfma_f32_16x16x32_f16(ao, b1f, acc[t], 0, 0, 0);
        }
    }

    // K-chunk 8: A = [S, F, 1, 0...], B rows = [w256; w257; b1; 0...]
    half8 aE;
    #pragma unroll
    for (int j = 0; j < 8; ++j) aE[j] = (_Float16)0.f;
    if (q == 0) {
        aE[0] = *(const _Float16*)&sl;
        aE[1] = *(const _Float16*)&fl;
        aE[2] = (_Float16)1.0f;
    }
    #pragma unroll
    for (int t = 0; t < 8; ++t) {
        const half8 bE = *(const half8*)&w1t[((t << 4) + cb) * W1T_STRIDE + ((32 + q) << 3)];
        acc[t] = __builtin_amdgcn_mfma_f32_16x16x32_f16(aE, bE, acc[t], 0, 0, 0);
    }

    // epilogue: silu(acc) dot W2 only (S/F/b1 already inside acc)
    int oe_r[4];
    #pragma unroll
    for (int rr = 0; rr < 4; ++rr) oe_r[rr] = __shfl(oe, (q << 2) + rr);

    float rs[4] = {0.f, 0.f, 0.f, 0.f};
    #pragma unroll
    for (int t = 0; t < 8; ++t) {
        const float w2c = (t < 4) ? w2a[t] : w2b[t - 4];
        const f32x4 av = acc[t];
        #pragma unroll
        for (int rr = 0; rr < 4; ++rr)
            rs[rr] += silu_f(av[rr]) * w2c;
    }

    #pragma unroll
    for (int off = 1; off < 16; off <<= 1) {
        #pragma unroll
        for (int rr = 0; rr < 4; ++rr) rs[rr] += __shfl_xor(rs[rr], off);
    }

    if (cb == 0) {
        #pragma unroll
        for (int rr = 0; rr < 4; ++rr) {
            const int pe = ebase + (q << 2) + rr;
            if (pe < elim) out[oe_r[rr]] = rs[rr] + b2v;
        }
    }
}

// ---------------- main kernel (R12 ticket skeleton + prefetch) ----------------

__global__ __launch_bounds__(512, 4)
void edgegate_seg(const _Float16* __restrict__ Hh,
                  const int4*  __restrict__ recs,
                  const int*   __restrict__ vbs,   // [9] segment edge bounds
                  int*         __restrict__ ctr,   // [8] per-segment ticket ctrs
                  const float* __restrict__ W1,
                  const float* __restrict__ b1,
                  const float* __restrict__ W2,
                  const float* __restrict__ b2,
                  float*       __restrict__ out)
{
    __shared__ _Float16 w1t[128 * W1T_STRIDE];   // 73,728 B
    __shared__ int tkt[2];                        // parity ticket slots
    const int tid = threadIdx.x;
    stage_w1(W1, b1, w1t, tid);

    int xcd;
    asm volatile("s_getreg_b32 %0, hwreg(HW_REG_XCC_ID)" : "=s"(xcd));
    xcd &= (NSEG - 1);

    const int lane = tid & 63;
    const int wave = tid >> 6;
    const int q    = lane >> 4;
    const int cb   = lane & 15;
    const int swz  = cb & 7;
    const float b2v = b2[0];
    f32x4 w2a, w2b;
    #pragma unroll
    for (int t = 0; t < 4; ++t) {
        w2a[t] = W2[(t << 4) + cb];
        w2b[t] = W2[((t + 4) << 4) + cb];
    }

    int p = 0;
    // own segment first, then steal (correct under any dispatch mapping)
    for (int sidx = 0; sidx < NSEG; ++sidx) {
        const int seg = (xcd + sidx) & (NSEG - 1);
        const int vs  = vbs[seg];
        const int ve  = vbs[seg + 1];
        const int ner = ve - vs;
        if (ner <= 0) continue;
        const int Tt = (ner + 127) >> 7;    // 128-edge tickets

        __syncthreads();                    // tkt[p] free; (also covers w1t on sidx==0)
        if (tid == 0) tkt[p] = atomicAdd(&ctr[seg], 1);
        __syncthreads();
        int t0 = tkt[p];
        while (t0 < Tt) {
            const int pn = p ^ 1;
            if (tid == 0) tkt[pn] = atomicAdd(&ctr[seg], 1);   // prefetch next
            const int ebase = vs + (t0 << 7) + (wave << 4);
            edge_tile16(Hh, recs, w1t, w2a, w2b, b2v, out, ebase, ve, q, cb, swz);
            __syncthreads();     // publishes tkt[pn]; paces the segment's blocks
            p = pn;
            t0 = tkt[p];
        }
    }
}

// ---------------- fallback (unsorted) ----------------

__global__ __launch_bounds__(512, 4)
void edgegate_fb(const float* __restrict__ H,
                 const _Float16* __restrict__ Hh,
                 const int*   __restrict__ eidx,
                 const float* __restrict__ Se,
                 const float* __restrict__ Fe,
                 const float* __restrict__ W1,
                 const float* __restrict__ b1,
                 const float* __restrict__ W2,
                 const float* __restrict__ b2,
                 float*       __restrict__ out,
                 int E, int ntiles, int useF16)
{
    __shared__ _Float16 w1t[128 * W1T_STRIDE];
    const int tid = threadIdx.x;
    stage_w1(W1, b1, w1t, tid);

    const int lane = tid & 63;
    const int wave = tid >> 6;
    const int q    = lane >> 4;
    const int cb   = lane & 15;
    const int swz  = cb & 7;
    const float b2v = b2[0];
    f32x4 w2a, w2b;
    #pragma unroll
    for (int t = 0; t < 4; ++t) {
        w2a[t] = W2[(t << 4) + cb];
        w2b[t] = W2[((t + 4) << 4) + cb];
    }

    __syncthreads();

    for (int tile = blockIdx.x; tile < ntiles; tile += gridDim.x) {
        const int ebase = tile * 128 + wave * 16;
        int e = ebase + cb;
        if (e >= E) e = E - 1;
        const int u = eidx[e];
        const int v = eidx[E + e];
        const float sfe = Se[e];
        const float ffe = Fe[e];

        f32x4 acc[8];
        #pragma unroll
        for (int t = 0; t < 8; ++t) acc[t] = (f32x4){0.f, 0.f, 0.f, 0.f};

        #pragma unroll
        for (int c8 = 0; c8 < 4; ++c8) {
            half8 ae, ao;
            if (useF16) {
                const _Float16* up = Hh + (size_t)u * 128;
                const _Float16* vp = Hh + (size_t)v * 128;
                const half8 u8 = *(const half8*)(up + (c8 << 5) + (q << 3));
                const half8 v8 = *(const half8*)(vp + (c8 << 5) + (q << 3));
                half8 d8 = u8 - v8;
                ushort8 du = *(ushort8*)&d8;
                du = du & (unsigned short)0x7FFF;
                ae = *(half8*)&du;
                ao = u8 * v8;
            } else {
                const float* up = H + (size_t)u * 128;
                const float* vp = H + (size_t)v * 128;
                #pragma unroll
                for (int j = 0; j < 8; ++j) {
                    const float uu = up[(c8 << 5) + (q << 3) + j];
                    const float vv = vp[(c8 << 5) + (q << 3) + j];
                    ae[j] = (_Float16)fabsf(uu - vv);
                    ao[j] = (_Float16)(uu * vv);
                }
            }
            const int kb0 = ((c8 << 3) + q) ^ swz;
            const int kb1 = ((c8 << 3) + 4 + q) ^ swz;
            #pragma unroll
            for (int t = 0; t < 8; ++t) {
                const half8 b0 = *(const half8*)&w1t[((t << 4) + cb) * W1T_STRIDE + (kb0 << 3)];
                acc[t] = __builtin_amdgcn_mfma_f32_16x16x32_f16(ae, b0, acc[t], 0, 0, 0);
            }
            #pragma unroll
            for (int t = 0; t < 8; ++t) {
                const half8 b1f = *(const half8*)&w1t[((t << 4) + cb) * W1T_STRIDE + (kb1 << 3)];
                acc[t] = __builtin_amdgcn_mfma_f32_16x16x32_f16(ao, b1f, acc[t], 0, 0, 0);
            }
        }

        // K-chunk 8
        half8 aE;
        #pragma unroll
        for (int j = 0; j < 8; ++j) aE[j] = (_Float16)0.f;
        if (q == 0) {
            aE[0] = (_Float16)sfe;
            aE[1] = (_Float16)ffe;
            aE[2] = (_Float16)1.0f;
        }
        #pragma unroll
        for (int t = 0; t < 8; ++t) {
            const half8 bE = *(const half8*)&w1t[((t << 4) + cb) * W1T_STRIDE + ((32 + q) << 3)];
            acc[t] = __builtin_amdgcn_mfma_f32_16x16x32_f16(aE, bE, acc[t], 0, 0, 0);
        }

        float rs[4] = {0.f, 0.f, 0.f, 0.f};
        #pragma unroll
        for (int t = 0; t < 8; ++t) {
            const float w2c = (t < 4) ? w2a[t] : w2b[t - 4];
            const f32x4 av = acc[t];
            #pragma unroll
            for (int rr = 0; rr < 4; ++rr)
                rs[rr] += silu_f(av[rr]) * w2c;
        }
        #pragma unroll
        for (int off = 1; off < 16; off <<= 1) {
            #pragma unroll
            for (int rr = 0; rr < 4; ++rr) rs[rr] += __shfl_xor(rs[rr], off);
        }

        const int e0 = ebase + (q << 2);
        if (cb == 0) {
            #pragma unroll
            for (int rr = 0; rr < 4; ++rr) {
                const int pe = e0 + rr;
                if (pe < E) out[pe] = rs[rr] + b2v;
            }
        }
    }
}

// ---------------- launch ----------------

static inline size_t align256(size_t x) { return (x + 255) & ~(size_t)255; }

extern "C" void kernel_launch(void* const* d_in, const int* in_sizes, int n_in,
                              void* d_out, int out_size, void* d_ws, size_t ws_size,
                              hipStream_t stream)
{
    const float* H    = (const float*)d_in[0];
    const int*   eidx = (const int*)  d_in[1];
    const float* Se   = (const float*)d_in[2];
    const float* Fe   = (const float*)d_in[3];
    const float* W1   = (const float*)d_in[4];
    const float* b1   = (const float*)d_in[5];
    const float* W2   = (const float*)d_in[6];
    const float* b2   = (const float*)d_in[7];
    float* out = (float*)d_out;

    const int nH     = in_sizes[0];            // 6.4M floats
    const int nNodes = nH / 128;               // 50000
    const int E      = in_sizes[2];            // 600000
    const int n4     = nH / 4;
    const int ntiles = (E + 127) / 128;

    const int ASZ   = (nNodes + NSEG - 1) / NSEG;   // 6250
    const int BBINS = (nNodes + 7) >> 3;            // 6250
    const int NB    = NSEG * BBINS;                 // 50000
    const int nb1   = (NB + 255) / 256;             // 196

    const size_t hhB    = (size_t)nH * sizeof(_Float16);
    const size_t off_g  = align256(hhB);                          // hist + ctr
    const size_t off_bs = align256(off_g + (size_t)(NB + 8) * 4); // bsum
    const size_t off_vb = align256(off_bs + 256 * 4);             // vbs[9]
    const size_t off_r  = align256(off_vb + 16 * 4);              // recs
    const size_t need   = off_r + (size_t)E * sizeof(int4);

    if (ws_size >= need && nb1 <= 256) {
        _Float16* Hh   = (_Float16*)((char*)d_ws);
        int*      hist = (int*)     ((char*)d_ws + off_g);
        int*      ctr  = hist + NB;                       // 8 counters
        int*      bsum = (int*)     ((char*)d_ws + off_bs);
        int*      vbs  = (int*)     ((char*)d_ws + off_vb);
        int4*     recs = (int4*)    ((char*)d_ws + off_r);

        const int ncvh = (n4 > E) ? n4 : E;
        hipMemsetAsync(hist, 0, (size_t)(NB + 8) * sizeof(int), stream);
        hipLaunchKernelGGL(cvt_hist_kernel, dim3((ncvh + 255) / 256), dim3(256),
                           0, stream, H, Hh, n4, eidx, hist, E, ASZ, BBINS);
        hipLaunchKernelGGL(scan1_kernel, dim3(nb1), dim3(256), 0, stream,
                           hist, bsum, NB);
        hipLaunchKernelGGL(scan2_kernel, dim3(1), dim3(256), 0, stream,
                           bsum, nb1, hist, vbs, BBINS, E);
        hipLaunchKernelGGL(scatter_kernel, dim3((E + 255) / 256), dim3(256),
                           0, stream, eidx, Se, Fe, hist, bsum, recs,
                           E, ASZ, BBINS);
        hipLaunchKernelGGL(edgegate_seg, dim3(512), dim3(512), 0, stream,
                           Hh, recs, vbs, ctr, W1, b1, W2, b2, out);
    } else if (ws_size >= hhB) {
        _Float16* Hh = (_Float16*)d_ws;
        const int grid = (512 < ntiles) ? 512 : ntiles;
        hipLaunchKernelGGL(cvt_hist_kernel, dim3((n4 + 255) / 256), dim3(256),
                           0, stream, H, Hh, n4, eidx, (int*)nullptr, 0, 1, 1);
        hipLaunchKernelGGL(edgegate_fb, dim3(grid), dim3(512), 0, stream,
                           H, Hh, eidx, Se, Fe, W1, b1, W2, b2, out, E, ntiles, 1);
    } else {
        const int grid = (512 < ntiles) ? 512 : ntiles;
        hipLaunchKernelGGL(edgegate_fb, dim3(grid), dim3(512), 0, stream,
                           H, (const _Float16*)nullptr, eidx, Se, Fe, W1, b1, W2, b2,
                           out, E, ntiles, 0);
    }
}